// Round 7
// baseline (92.192 us; speedup 1.0000x reference)
//
#include <hip/hip_runtime.h>
#include <hip/hip_bf16.h>

// Problem constants
#define B_  2
#define L_  2048
#define C_  1024
#define H_  16
#define K_  32
#define DH_ 64
#define M_  (B_ * L_)   // 4096 rows in all GEMMs

typedef __hip_bfloat16 bf16;
typedef __attribute__((ext_vector_type(4))) float f32x4;
typedef __attribute__((ext_vector_type(8))) short short8;
typedef __attribute__((ext_vector_type(8))) unsigned short u16x8;

__device__ inline unsigned short f2bf(float f) {
    __hip_bfloat16 h = __float2bfloat16(f);  // RTN
    return *reinterpret_cast<unsigned short*>(&h);
}
__device__ inline float bf2f(unsigned short u) {
    return __uint_as_float(((unsigned)u) << 16);
}
__device__ inline void gld_lds16(const bf16* g, bf16* l) {
    __builtin_amdgcn_global_load_lds(
        (const __attribute__((address_space(1))) void*)g,
        (__attribute__((address_space(3))) void*)l,
        16, 0, 0);
}

// ---------------------------------------------------------------------------
// Kernel 1: convert x, Wq, Wk, Wv, Wo from f32 to bf16 (one fused launch).
// ---------------------------------------------------------------------------
__global__ void __launch_bounds__(256) cvt_all(
    const float* __restrict__ x,  const float* __restrict__ wq,
    const float* __restrict__ wk, const float* __restrict__ wv,
    const float* __restrict__ wo,
    bf16* __restrict__ xb,  bf16* __restrict__ wqb, bf16* __restrict__ wkb,
    bf16* __restrict__ wvb, bf16* __restrict__ wob)
{
    int g = blockIdx.x * 256 + threadIdx.x;
    const float* src; bf16* dst; int o;
    if (g < 1048576)      { src = x;  dst = xb;  o = g; }
    else if (g < 1310720) { src = wq; dst = wqb; o = g - 1048576; }
    else if (g < 1572864) { src = wk; dst = wkb; o = g - 1310720; }
    else if (g < 1835008) { src = wv; dst = wvb; o = g - 1572864; }
    else                  { src = wo; dst = wob; o = g - 1835008; }
    float4 f = reinterpret_cast<const float4*>(src)[o];
    ushort4 u;
    u.x = f2bf(f.x); u.y = f2bf(f.y); u.z = f2bf(f.z); u.w = f2bf(f.w);
    reinterpret_cast<ushort4*>(dst)[o] = u;
}

// ---------------------------------------------------------------------------
// Kernel 2: QKV GEMM, counted-vmcnt deep pipeline (T3+T4+T5).
// Y = x @ [Wq|Wk|Wv]^T.  M=4096, N=3072, K=1024.  BM=BN=256, BK=64,
// 512 thr = 8 waves, per-wave C = 256 rows x 32 cols (full height slice).
// LDS 128 KiB = 2 bufs x 4 half-tiles (ht0=A rows0-127, ht1=B0, ht2=B1,
// ht3=A rows128-255), each 128x64 bf16.  Stage order ht0,ht1,ht2,ht3.
// Two phases per K-tile:
//   S1 (C rows 0-127):  needs ht0,ht1,ht2 -> s_waitcnt vmcnt(2); raw barrier;
//                       stage next-tile ht0,ht1; ds_read; 32 MFMA (setprio).
//   S2 (C rows 128-255):needs ht3         -> s_waitcnt vmcnt(4); raw barrier;
//                       stage next-tile ht2,ht3; ds_read; 32 MFMA.
// vmcnt is never 0 mid-loop (loads span phases); tail drains with vmcnt(0).
// Swizzle: m97's verified pattern — src chunk ^= row&7, LDS linear, read
// chunk ^= row&7 (both-sides, rule #21).
// ---------------------------------------------------------------------------
struct Gemm8Args {
    const bf16* A;
    const bf16* W[3];
    bf16* Y[3];
    float scale0;
};

// stage one 128x64 half-tile (2 gld_lds per thread, 8 waves x 2 passes)
#define STGH(bufn, ht, Gptr, rbase, kt) {                                    \
    _Pragma("unroll")                                                        \
    for (int i_ = 0; i_ < 2; ++i_) {                                         \
        const int row_ = i_ * 64 + w * 8 + (lane >> 3);                      \
        const int ch_  = (lane & 7) ^ (row_ & 7);                            \
        gld_lds16((Gptr) + (size_t)((rbase) + row_) * 1024 + (kt) * 64 + ch_ * 8, \
                  smb + (size_t)(bufn) * 32768 + (ht) * 8192                 \
                      + (i_ * 64 + w * 8) * 64);                             \
    }                                                                        \
}

#define RDA(bufn, ah, ks) {                                                  \
    _Pragma("unroll")                                                        \
    for (int mf = 0; mf < 8; ++mf) {                                         \
        const int r_ = mf * 16 + (lane & 15);                                \
        const int c_ = ((ks) * 4 + (lane >> 4)) ^ (r_ & 7);                  \
        ak[mf] = *reinterpret_cast<const short8*>(                           \
            smb + (size_t)(bufn) * 32768 + (ah) * 8192 + r_ * 64 + c_ * 8);  \
    }                                                                        \
}

#define RDB(bufn, ks) {                                                      \
    _Pragma("unroll")                                                        \
    for (int nf = 0; nf < 2; ++nf) {                                         \
        const int c_col = wn * 32 + nf * 16 + (lane & 15);                   \
        const int bh_   = 1 + (c_col >> 7);                                  \
        const int r_    = c_col & 127;                                       \
        const int c_    = ((ks) * 4 + (lane >> 4)) ^ (r_ & 7);               \
        bk[nf] = *reinterpret_cast<const short8*>(                           \
            smb + (size_t)(bufn) * 32768 + bh_ * 8192 + r_ * 64 + c_ * 8);   \
    }                                                                        \
}

#define MAC(p) {                                                             \
    __builtin_amdgcn_s_setprio(1);                                           \
    _Pragma("unroll")                                                        \
    for (int mf = 0; mf < 8; ++mf)                                           \
        _Pragma("unroll")                                                    \
        for (int nf = 0; nf < 2; ++nf)                                       \
            acc[p][mf][nf] = __builtin_amdgcn_mfma_f32_16x16x32_bf16(        \
                ak[mf], bk[nf], acc[p][mf][nf], 0, 0, 0);                    \
    __builtin_amdgcn_s_setprio(0);                                           \
}

__global__ void __launch_bounds__(512, 1) gemm8_qkv(Gemm8Args ga)
{
    extern __shared__ __align__(16) char smraw[];
    bf16* smb = (bf16*)smraw;

    // bijective XCD swizzle: 192 blocks, 192 % 8 == 0 -> 24 per XCD;
    // consecutive nid within an XCD share bn (W-panel reuse in L2).
    const int bid = blockIdx.x;
    const int nid = (bid & 7) * 24 + (bid >> 3);
    const int bm  = nid & 15;           // 16 M-tiles
    const int bn  = nid >> 4;           // 12 N-tiles
    const int m0  = bm * 256;
    const int seg = bn >> 2;            // 0..2 -> Wq/Wk/Wv
    const int nw0 = (bn & 3) * 256;

    const bf16* __restrict__ A = ga.A;
    const bf16* __restrict__ W = ga.W[seg];
    bf16* __restrict__ Y = ga.Y[seg];
    const float scale = (seg == 0) ? ga.scale0 : 1.0f;

    const int tid  = threadIdx.x;
    const int lane = tid & 63;
    const int w    = tid >> 6;          // wave 0..7
    const int wn   = w;                 // wave's 32-col slice

    f32x4 acc[2][8][2] = {};
    short8 ak[8], bk[2];

    // prologue: stage K-tile 0 (ht0,ht1,ht2,ht3) into buf 0 -> 8 glds/thread
    STGH(0, 0, A, m0,        0);
    STGH(0, 1, W, nw0,       0);
    STGH(0, 2, W, nw0 + 128, 0);
    STGH(0, 3, A, m0 + 128,  0);

    #pragma unroll 1
    for (int t = 0; t < 16; ++t) {
        const int cur = t & 1;
        const int nxt = cur ^ 1;
        const bool more = (t < 15);

        // ---- S1: C rows 0-127 ----
        asm volatile("s_waitcnt vmcnt(2)" ::: "memory");
        __builtin_amdgcn_s_barrier();
        if (more) {
            STGH(nxt, 0, A, m0,  t + 1);
            STGH(nxt, 1, W, nw0, t + 1);
        }
        RDA(cur, 0, 0); RDB(cur, 0);
        MAC(0);
        RDA(cur, 0, 1); RDB(cur, 1);
        MAC(0);

        // ---- S2: C rows 128-255 ----
        if (more) asm volatile("s_waitcnt vmcnt(4)" ::: "memory");
        else      asm volatile("s_waitcnt vmcnt(0)" ::: "memory");
        __builtin_amdgcn_s_barrier();
        if (more) {
            STGH(nxt, 2, W, nw0 + 128, t + 1);
            STGH(nxt, 3, A, m0 + 128,  t + 1);
        }
        RDA(cur, 3, 0); RDB(cur, 0);
        MAC(1);
        RDA(cur, 3, 1); RDB(cur, 1);
        MAC(1);
    }

    // epilogue: C/D layout col=lane&15, row=(lane>>4)*4+r
    #pragma unroll
    for (int p = 0; p < 2; ++p) {
        #pragma unroll
        for (int mf = 0; mf < 8; ++mf) {
            #pragma unroll
            for (int nf = 0; nf < 2; ++nf) {
                const int row = m0 + p * 128 + mf * 16 + ((lane >> 4) << 2);
                const int col = nw0 + wn * 32 + nf * 16 + (lane & 15);
                #pragma unroll
                for (int r = 0; r < 4; ++r)
                    Y[(size_t)(row + r) * 1024 + col] =
                        __float2bfloat16(acc[p][mf][nf][r] * scale);
            }
        }
    }
}

// ---------------------------------------------------------------------------
// Kernel 4: output projection NT GEMM, 128x64 tile -> grid (32,16) = 512
// blocks = 2/CU.  f32 output to d_out.
// ---------------------------------------------------------------------------
__global__ void __launch_bounds__(256) gemm_out(
    const bf16* __restrict__ A, const bf16* __restrict__ W,
    float* __restrict__ Yf)
{
    __shared__ bf16 As[128 * 64];   // 16 KiB
    __shared__ bf16 Bs[64 * 64];    // 8 KiB

    const int m0 = blockIdx.x * 128;
    const int n0 = blockIdx.y * 64;

    const int t    = threadIdx.x;
    const int lane = t & 63;
    const int w    = t >> 6;
    const int wm   = w >> 1;    // 0..1
    const int wn   = w & 1;     // 0..1

    const int subrow = lane >> 3;
    const int kc     = lane & 7;

    f32x4 acc[4][2] = {};

    for (int kt = 0; kt < 16; ++kt) {
        const int k0 = kt * 64;
        if (kt) __syncthreads();
        #pragma unroll
        for (int i = 0; i < 4; ++i) {
            const int r0  = w * 32 + i * 8;
            const int row = r0 + subrow;
            const int kcs = kc ^ (subrow & 7);
            gld_lds16(A + (size_t)(m0 + row) * 1024 + k0 + kcs * 8, As + r0 * 64);
        }
        #pragma unroll
        for (int i = 0; i < 2; ++i) {
            const int r0  = w * 16 + i * 8;
            const int row = r0 + subrow;
            const int kcs = kc ^ (subrow & 7);
            gld_lds16(W + (size_t)(n0 + row) * 1024 + k0 + kcs * 8, Bs + r0 * 64);
        }
        __syncthreads();
        #pragma unroll
        for (int ks = 0; ks < 2; ++ks) {
            short8 af[4], bfv[2];
            #pragma unroll
            for (int mf = 0; mf < 4; ++mf) {
                const int row    = wm * 64 + mf * 16 + (lane & 15);
                const int kchunk = ks * 4 + (lane >> 4);
                const int pc     = kchunk ^ (row & 7);
                af[mf] = *reinterpret_cast<const short8*>(As + row * 64 + pc * 8);
            }
            #pragma unroll
            for (int nf = 0; nf < 2; ++nf) {
                const int row    = wn * 32 + nf * 16 + (lane & 15);
                const int kchunk = ks * 4 + (lane >> 4);
                const int pc     = kchunk ^ (row & 7);
                bfv[nf] = *reinterpret_cast<const short8*>(Bs + row * 64 + pc * 8);
            }
            #pragma unroll
            for (int mf = 0; mf < 4; ++mf)
                #pragma unroll
                for (int nf = 0; nf < 2; ++nf)
                    acc[mf][nf] = __builtin_amdgcn_mfma_f32_16x16x32_bf16(
                        af[mf], bfv[nf], acc[mf][nf], 0, 0, 0);
        }
    }

    #pragma unroll
    for (int mf = 0; mf < 4; ++mf) {
        #pragma unroll
        for (int nf = 0; nf < 2; ++nf) {
            const int row = m0 + wm * 64 + mf * 16 + ((lane >> 4) << 2);
            const int col = n0 + wn * 32 + nf * 16 + (lane & 15);
            #pragma unroll
            for (int r = 0; r < 4; ++r)
                Yf[(size_t)(row + r) * 1024 + col] = acc[mf][nf][r];
        }
    }
}

// ---------------------------------------------------------------------------
// Kernel 3: K=32 neighbor attention — wave-synchronous, no LDS/barriers.
// 4-wave blocks (wave ww -> l = l0+ww), slot = b*4+wg pinned to XCD via
// blockIdx.x; occupancy at the 32-waves/CU cap.
// ---------------------------------------------------------------------------
__global__ void __launch_bounds__(256) attn_knn(
    const bf16* __restrict__ qg, const bf16* __restrict__ kg,
    const bf16* __restrict__ vg, const int* __restrict__ idx,
    bf16* __restrict__ ao)
{
    const int slot = blockIdx.x;      // 0..7 -> XCD (bid%8 heuristic)
    const int b    = slot >> 2;
    const int wg   = slot & 3;
    const int l    = blockIdx.y * 4 + (threadIdx.x >> 6);

    const int lane = threadIdx.x & 63;
    const int hw   = lane >> 4;       // head within group
    const int h    = wg * 4 + hw;
    const int sl   = lane & 15;
    const int half = sl >> 3;
    const int c8   = sl & 7;

    const size_t rowq = (size_t)b * L_ + l;
    const unsigned short* kg16 = reinterpret_cast<const unsigned short*>(kg);
    const unsigned short* vg16 = reinterpret_cast<const unsigned short*>(vg);
    const size_t hoff = (size_t)h * DH_ + c8 * 8;

    int4 iv[4];
    #pragma unroll
    for (int i = 0; i < 4; ++i)
        iv[i] = reinterpret_cast<const int4*>(idx + l * K_ + half * 16)[i];

    u16x8 qv = *reinterpret_cast<const u16x8*>(
        reinterpret_cast<const unsigned short*>(qg) + rowq * C_ + hoff);
    float qf[8];
    #pragma unroll
    for (int e = 0; e < 8; ++e) qf[e] = bf2f(qv[e]);

    float s[16];
    #pragma unroll
    for (int jj = 0; jj < 16; ++jj) {
        const int4 q4 = iv[jj >> 2];
        const int row = (jj & 3) == 0 ? q4.x : (jj & 3) == 1 ? q4.y
                       : (jj & 3) == 2 ? q4.z : q4.w;
        const u16x8 kv = *reinterpret_cast<const u16x8*>(
            kg16 + ((size_t)b * L_ + row) * C_ + hoff);
        float acc = 0.f;
        #pragma unroll
        for (int e = 0; e < 8; ++e) acc += qf[e] * bf2f(kv[e]);
        s[jj] = acc;
    }

    #pragma unroll
    for (int jj = 0; jj < 16; ++jj) {
        float x = s[jj];
        x += __shfl_xor(x, 1, 16);
        x += __shfl_xor(x, 2, 16);
        x += __shfl_xor(x, 4, 16);
        s[jj] = x;
    }

    float m = s[0];
    #pragma unroll
    for (int jj = 1; jj < 16; ++jj) m = fmaxf(m, s[jj]);
    m = fmaxf(m, __shfl_xor(m, 8, 16));
    float ssum = 0.f;
    #pragma unroll
    for (int jj = 0; jj < 16; ++jj) { s[jj] = __expf(s[jj] - m); ssum += s[jj]; }
    ssum += __shfl_xor(ssum, 8, 16);
    const float inv = 1.0f / ssum;

    float acc[8] = {0.f, 0.f, 0.f, 0.f, 0.f, 0.f, 0.f, 0.f};
    #pragma unroll
    for (int jj = 0; jj < 16; ++jj) {
        const int4 q4 = iv[jj >> 2];
        const int row = (jj & 3) == 0 ? q4.x : (jj & 3) == 1 ? q4.y
                       : (jj & 3) == 2 ? q4.z : q4.w;
        const u16x8 vv = *reinterpret_cast<const u16x8*>(
            vg16 + ((size_t)b * L_ + row) * C_ + hoff);
        const float p = s[jj];
        #pragma unroll
        for (int e = 0; e < 8; ++e) acc[e] += p * bf2f(vv[e]);
    }
    #pragma unroll
    for (int e = 0; e < 8; ++e) acc[e] += __shfl_xor(acc[e], 8, 16);

    if (half == 0) {
        u16x8 o;
        #pragma unroll
        for (int e = 0; e < 8; ++e) o[e] = f2bf(acc[e] * inv);
        *reinterpret_cast<u16x8*>(ao + rowq * C_ + hoff) = o;
    }
}

// ---------------------------------------------------------------------------
// Launcher. Workspace layout (bytes):
//   xb 0 (8 MiB) | wqb 8M | wkb 10M | wvb 12M | wob 14M (2 MiB each)
//   q 16M | k 24M | v 32M | ao 40M  (8 MiB each)  -> total 48 MiB
// ---------------------------------------------------------------------------
extern "C" void kernel_launch(void* const* d_in, const int* in_sizes, int n_in,
                              void* d_out, int out_size, void* d_ws, size_t ws_size,
                              hipStream_t stream)
{
    const float* x  = (const float*)d_in[0];
    const int*   idx = (const int*)d_in[1];
    const float* Wq = (const float*)d_in[2];
    const float* Wk = (const float*)d_in[3];
    const float* Wv = (const float*)d_in[4];
    const float* Wo = (const float*)d_in[5];
    float* out = (float*)d_out;

    char* ws = (char*)d_ws;
    bf16* xb  = (bf16*)(ws + 0);
    bf16* wqb = (bf16*)(ws + 8388608);
    bf16* wkb = (bf16*)(ws + 10485760);
    bf16* wvb = (bf16*)(ws + 12582912);
    bf16* wob = (bf16*)(ws + 14680064);
    bf16* qb  = (bf16*)(ws + 16777216);
    bf16* kb  = (bf16*)(ws + 25165824);
    bf16* vb  = (bf16*)(ws + 33554432);
    bf16* ab  = (bf16*)(ws + 41943040);

    cvt_all<<<8192, 256, 0, stream>>>(x, Wq, Wk, Wv, Wo, xb, wqb, wkb, wvb, wob);

    Gemm8Args g1;
    g1.A = xb;
    g1.W[0] = wqb; g1.W[1] = wkb; g1.W[2] = wvb;
    g1.Y[0] = qb;  g1.Y[1] = kb;  g1.Y[2] = vb;
    g1.scale0 = 0.125f;   // 1/sqrt(Dh)
    gemm8_qkv<<<192, 512, 131072, stream>>>(g1);

    attn_knn<<<dim3(8, 512), 256, 0, stream>>>(qb, kb, vb, idx, ab);

    gemm_out<<<dim3(32, 16), 256, 0, stream>>>(ab, wob, out);
}

// Round 8
// 88.867 us; speedup vs baseline: 1.0374x; 1.0374x over previous
//
#include <hip/hip_runtime.h>
#include <hip/hip_bf16.h>

// Problem constants
#define B_  2
#define L_  2048
#define C_  1024
#define H_  16
#define K_  32
#define DH_ 64
#define M_  (B_ * L_)   // 4096 rows in all GEMMs

typedef __hip_bfloat16 bf16;
typedef __attribute__((ext_vector_type(4))) float f32x4;
typedef __attribute__((ext_vector_type(8))) short short8;
typedef __attribute__((ext_vector_type(8))) unsigned short u16x8;

__device__ inline unsigned short f2bf(float f) {
    __hip_bfloat16 h = __float2bfloat16(f);  // RTN
    return *reinterpret_cast<unsigned short*>(&h);
}
__device__ inline float bf2f(unsigned short u) {
    return __uint_as_float(((unsigned)u) << 16);
}
__device__ inline void gld_lds16(const bf16* g, bf16* l) {
    __builtin_amdgcn_global_load_lds(
        (const __attribute__((address_space(1))) void*)g,
        (__attribute__((address_space(3))) void*)l,
        16, 0, 0);
}

// ---------------------------------------------------------------------------
// Kernel 1: convert x, Wq, Wk, Wv, Wo from f32 to bf16 (one fused launch).
// Memory-bound (~36 MB traffic -> ~6-8 us).
// ---------------------------------------------------------------------------
__global__ void __launch_bounds__(256) cvt_all(
    const float* __restrict__ x,  const float* __restrict__ wq,
    const float* __restrict__ wk, const float* __restrict__ wv,
    const float* __restrict__ wo,
    bf16* __restrict__ xb,  bf16* __restrict__ wqb, bf16* __restrict__ wkb,
    bf16* __restrict__ wvb, bf16* __restrict__ wob)
{
    int g = blockIdx.x * 256 + threadIdx.x;
    const float* src; bf16* dst; int o;
    if (g < 1048576)      { src = x;  dst = xb;  o = g; }
    else if (g < 1310720) { src = wq; dst = wqb; o = g - 1048576; }
    else if (g < 1572864) { src = wk; dst = wkb; o = g - 1310720; }
    else if (g < 1835008) { src = wv; dst = wvb; o = g - 1572864; }
    else                  { src = wo; dst = wob; o = g - 1835008; }
    float4 f = reinterpret_cast<const float4*>(src)[o];
    ushort4 u;
    u.x = f2bf(f.x); u.y = f2bf(f.y); u.z = f2bf(f.z); u.w = f2bf(f.w);
    reinterpret_cast<ushort4*>(dst)[o] = u;
}

// ---------------------------------------------------------------------------
// Kernel 2: QKV NT GEMM  Y = x @ [Wq|Wk|Wv]^T  (m97 128^2 structure).
// grid (32, 24) = 768 blocks = 3/CU (implicit wave-level overlap regime).
// global_load_lds(16B) with both-sides XOR swizzle.
// ---------------------------------------------------------------------------
struct GemmArgs {
    const bf16* A;
    const bf16* W[3];
    bf16* Yb[3];
    float scale0;
};

__global__ void __launch_bounds__(256) gemm_qkv(GemmArgs ga)
{
    __shared__ bf16 As[128 * 64];   // 16 KiB
    __shared__ bf16 Bs[128 * 64];   // 16 KiB

    const int m0  = blockIdx.x * 128;
    const int nt  = blockIdx.y;
    const int seg = nt >> 3;            // 0..2 -> Wq/Wk/Wv
    const int n0  = (nt & 7) * 128;
    const bf16* __restrict__ A = ga.A;
    const bf16* __restrict__ W = ga.W[seg];
    const float scale = (seg == 0) ? ga.scale0 : 1.0f;

    const int t    = threadIdx.x;
    const int lane = t & 63;
    const int w    = t >> 6;    // wave 0..3
    const int wm   = w >> 1;    // 0..1
    const int wn   = w & 1;     // 0..1

    const int subrow = lane >> 3;   // 0..7 within an 8-row staging inst
    const int kc     = lane & 7;    // 16B chunk 0..7 within a 64-elem k row

    f32x4 acc[4][4] = {};

    for (int kt = 0; kt < 16; ++kt) {
        const int k0 = kt * 64;
        if (kt) __syncthreads();
        #pragma unroll
        for (int i = 0; i < 4; ++i) {
            const int r0  = w * 32 + i * 8;
            const int row = r0 + subrow;
            const int kcs = kc ^ (subrow & 7);   // inverse swizzle on source
            gld_lds16(A + (size_t)(m0 + row) * 1024 + k0 + kcs * 8, As + r0 * 64);
        }
        #pragma unroll
        for (int i = 0; i < 4; ++i) {
            const int r0  = w * 32 + i * 8;
            const int row = r0 + subrow;
            const int kcs = kc ^ (subrow & 7);
            gld_lds16(W + (size_t)(n0 + row) * 1024 + k0 + kcs * 8, Bs + r0 * 64);
        }
        __syncthreads();
        #pragma unroll
        for (int ks = 0; ks < 2; ++ks) {
            short8 af[4], bfv[4];
            #pragma unroll
            for (int mf = 0; mf < 4; ++mf) {
                const int row    = wm * 64 + mf * 16 + (lane & 15);
                const int kchunk = ks * 4 + (lane >> 4);
                const int pc     = kchunk ^ (row & 7);   // swizzled read
                af[mf] = *reinterpret_cast<const short8*>(As + row * 64 + pc * 8);
            }
            #pragma unroll
            for (int nf = 0; nf < 4; ++nf) {
                const int row    = wn * 64 + nf * 16 + (lane & 15);
                const int kchunk = ks * 4 + (lane >> 4);
                const int pc     = kchunk ^ (row & 7);
                bfv[nf] = *reinterpret_cast<const short8*>(Bs + row * 64 + pc * 8);
            }
            #pragma unroll
            for (int mf = 0; mf < 4; ++mf)
                #pragma unroll
                for (int nf = 0; nf < 4; ++nf)
                    acc[mf][nf] = __builtin_amdgcn_mfma_f32_16x16x32_bf16(
                        af[mf], bfv[nf], acc[mf][nf], 0, 0, 0);
        }
    }

    #pragma unroll
    for (int mf = 0; mf < 4; ++mf) {
        #pragma unroll
        for (int nf = 0; nf < 4; ++nf) {
            const int row = m0 + wm * 64 + mf * 16 + ((lane >> 4) << 2);
            const int col = n0 + wn * 64 + nf * 16 + (lane & 15);
            #pragma unroll
            for (int r = 0; r < 4; ++r)
                ga.Yb[seg][(size_t)(row + r) * 1024 + col] =
                    __float2bfloat16(acc[mf][nf][r] * scale);
        }
    }
}

// ---------------------------------------------------------------------------
// Kernel 4: output projection NT GEMM, 128x64 tile -> grid (32,16) = 512
// blocks = 2/CU (cross-block overlap of the per-K-tile barrier drain).
// f32 output to d_out.
// ---------------------------------------------------------------------------
__global__ void __launch_bounds__(256) gemm_out(
    const bf16* __restrict__ A, const bf16* __restrict__ W,
    float* __restrict__ Yf)
{
    __shared__ bf16 As[128 * 64];   // 16 KiB
    __shared__ bf16 Bs[64 * 64];    // 8 KiB

    const int m0 = blockIdx.x * 128;
    const int n0 = blockIdx.y * 64;

    const int t    = threadIdx.x;
    const int lane = t & 63;
    const int w    = t >> 6;
    const int wm   = w >> 1;    // 0..1
    const int wn   = w & 1;     // 0..1

    const int subrow = lane >> 3;
    const int kc     = lane & 7;

    f32x4 acc[4][2] = {};

    for (int kt = 0; kt < 16; ++kt) {
        const int k0 = kt * 64;
        if (kt) __syncthreads();
        #pragma unroll
        for (int i = 0; i < 4; ++i) {
            const int r0  = w * 32 + i * 8;
            const int row = r0 + subrow;
            const int kcs = kc ^ (subrow & 7);
            gld_lds16(A + (size_t)(m0 + row) * 1024 + k0 + kcs * 8, As + r0 * 64);
        }
        #pragma unroll
        for (int i = 0; i < 2; ++i) {
            const int r0  = w * 16 + i * 8;
            const int row = r0 + subrow;
            const int kcs = kc ^ (subrow & 7);
            gld_lds16(W + (size_t)(n0 + row) * 1024 + k0 + kcs * 8, Bs + r0 * 64);
        }
        __syncthreads();
        #pragma unroll
        for (int ks = 0; ks < 2; ++ks) {
            short8 af[4], bfv[2];
            #pragma unroll
            for (int mf = 0; mf < 4; ++mf) {
                const int row    = wm * 64 + mf * 16 + (lane & 15);
                const int kchunk = ks * 4 + (lane >> 4);
                const int pc     = kchunk ^ (row & 7);
                af[mf] = *reinterpret_cast<const short8*>(As + row * 64 + pc * 8);
            }
            #pragma unroll
            for (int nf = 0; nf < 2; ++nf) {
                const int row    = wn * 32 + nf * 16 + (lane & 15);
                const int kchunk = ks * 4 + (lane >> 4);
                const int pc     = kchunk ^ (row & 7);
                bfv[nf] = *reinterpret_cast<const short8*>(Bs + row * 64 + pc * 8);
            }
            #pragma unroll
            for (int mf = 0; mf < 4; ++mf)
                #pragma unroll
                for (int nf = 0; nf < 2; ++nf)
                    acc[mf][nf] = __builtin_amdgcn_mfma_f32_16x16x32_bf16(
                        af[mf], bfv[nf], acc[mf][nf], 0, 0, 0);
        }
    }

    #pragma unroll
    for (int mf = 0; mf < 4; ++mf) {
        #pragma unroll
        for (int nf = 0; nf < 2; ++nf) {
            const int row = m0 + wm * 64 + mf * 16 + ((lane >> 4) << 2);
            const int col = n0 + wn * 32 + nf * 16 + (lane & 15);
            #pragma unroll
            for (int r = 0; r < 4; ++r)
                Yf[(size_t)(row + r) * 1024 + col] = acc[mf][nf][r];
        }
    }
}

// ---------------------------------------------------------------------------
// Kernel 3: K=32 neighbor attention — wave-synchronous, no LDS, no barriers.
// 4-wave blocks (wave ww -> l = l0+ww), slot = b*4+wg pinned to XCD via
// blockIdx.x (bid%8); occupancy at the 32-waves/CU cap.
// NEW (round 8): 32-bit gather addressing. Byte offset
//   boff[jj] = (row<<11) + (h*128 + c8*16)
// computed ONCE and reused for both k and v gathers (identical buffer
// geometry) against uniform SGPR bases -> 1 v_lshl_add_u32 + 1 load per
// gather instead of a 64-bit address chain, and no recompute in PV.
// ---------------------------------------------------------------------------
__global__ void __launch_bounds__(256) attn_knn(
    const bf16* __restrict__ qg, const bf16* __restrict__ kg,
    const bf16* __restrict__ vg, const int* __restrict__ idx,
    bf16* __restrict__ ao)
{
    const int slot = blockIdx.x;      // 0..7 -> XCD (bid%8 heuristic)
    const int b    = slot >> 2;
    const int wg   = slot & 3;
    const int l    = blockIdx.y * 4 + (threadIdx.x >> 6);

    const int lane = threadIdx.x & 63;
    const int hw   = lane >> 4;       // head within group
    const int h    = wg * 4 + hw;
    const int sl   = lane & 15;
    const int half = sl >> 3;
    const int c8   = sl & 7;

    const unsigned rowq  = (unsigned)b * L_ + (unsigned)l;
    const unsigned hoffB = (unsigned)h * 128u + (unsigned)c8 * 16u; // bytes
    const char* kbase = reinterpret_cast<const char*>(kg) + ((size_t)b << 22);
    const char* vbase = reinterpret_cast<const char*>(vg) + ((size_t)b << 22);

    int4 iv[4];
    #pragma unroll
    for (int i = 0; i < 4; ++i)
        iv[i] = reinterpret_cast<const int4*>(idx + l * K_ + half * 16)[i];

    // byte offsets shared by k and v gathers
    unsigned boff[16];
    #pragma unroll
    for (int jj = 0; jj < 16; ++jj) {
        const int4 q4 = iv[jj >> 2];
        const int row = (jj & 3) == 0 ? q4.x : (jj & 3) == 1 ? q4.y
                       : (jj & 3) == 2 ? q4.z : q4.w;
        boff[jj] = ((unsigned)row << 11) + hoffB;
    }

    u16x8 qv = *reinterpret_cast<const u16x8*>(
        reinterpret_cast<const char*>(qg) + ((size_t)rowq << 11) + hoffB);
    float qf[8];
    #pragma unroll
    for (int e = 0; e < 8; ++e) qf[e] = bf2f(qv[e]);

    // ---- QK^T partial dots (16 independent 16B gathers) ----
    float s[16];
    #pragma unroll
    for (int jj = 0; jj < 16; ++jj) {
        const u16x8 kv = *reinterpret_cast<const u16x8*>(kbase + boff[jj]);
        float acc = 0.f;
        #pragma unroll
        for (int e = 0; e < 8; ++e) acc += qf[e] * bf2f(kv[e]);
        s[jj] = acc;
    }

    // reduce partial dots across the 8-lane c8 group
    #pragma unroll
    for (int jj = 0; jj < 16; ++jj) {
        float x = s[jj];
        x += __shfl_xor(x, 1, 16);
        x += __shfl_xor(x, 2, 16);
        x += __shfl_xor(x, 4, 16);
        s[jj] = x;   // full score for j = half*16 + jj, in all 8 lanes
    }

    // ---- softmax in registers; 1/sum deferred to the store ----
    float m = s[0];
    #pragma unroll
    for (int jj = 1; jj < 16; ++jj) m = fmaxf(m, s[jj]);
    m = fmaxf(m, __shfl_xor(m, 8, 16));
    float ssum = 0.f;
    #pragma unroll
    for (int jj = 0; jj < 16; ++jj) { s[jj] = __expf(s[jj] - m); ssum += s[jj]; }
    ssum += __shfl_xor(ssum, 8, 16);
    const float inv = 1.0f / ssum;

    // ---- PV (16 independent 16B gathers, offsets reused) ----
    float acc[8] = {0.f, 0.f, 0.f, 0.f, 0.f, 0.f, 0.f, 0.f};
    #pragma unroll
    for (int jj = 0; jj < 16; ++jj) {
        const u16x8 vv = *reinterpret_cast<const u16x8*>(vbase + boff[jj]);
        const float p = s[jj];
        #pragma unroll
        for (int e = 0; e < 8; ++e) acc[e] += p * bf2f(vv[e]);
    }
    #pragma unroll
    for (int e = 0; e < 8; ++e) acc[e] += __shfl_xor(acc[e], 8, 16);

    if (half == 0) {
        u16x8 o;
        #pragma unroll
        for (int e = 0; e < 8; ++e) o[e] = f2bf(acc[e] * inv);
        *reinterpret_cast<u16x8*>(
            reinterpret_cast<char*>(ao) + ((size_t)rowq << 11) + hoffB) = o;
    }
}

// ---------------------------------------------------------------------------
// Launcher. Workspace layout (bytes):
//   xb 0 (8 MiB) | wqb 8M | wkb 10M | wvb 12M | wob 14M (2 MiB each)
//   q 16M | k 24M | v 32M | ao 40M  (8 MiB each)  -> total 48 MiB
// k and v blocks are 4 MiB per batch (b<<22 byte stride), row stride 2 KiB.
// ---------------------------------------------------------------------------
extern "C" void kernel_launch(void* const* d_in, const int* in_sizes, int n_in,
                              void* d_out, int out_size, void* d_ws, size_t ws_size,
                              hipStream_t stream)
{
    const float* x  = (const float*)d_in[0];
    const int*   idx = (const int*)d_in[1];
    const float* Wq = (const float*)d_in[2];
    const float* Wk = (const float*)d_in[3];
    const float* Wv = (const float*)d_in[4];
    const float* Wo = (const float*)d_in[5];
    float* out = (float*)d_out;

    char* ws = (char*)d_ws;
    bf16* xb  = (bf16*)(ws + 0);
    bf16* wqb = (bf16*)(ws + 8388608);
    bf16* wkb = (bf16*)(ws + 10485760);
    bf16* wvb = (bf16*)(ws + 12582912);
    bf16* wob = (bf16*)(ws + 14680064);
    bf16* qb  = (bf16*)(ws + 16777216);
    bf16* kb  = (bf16*)(ws + 25165824);
    bf16* vb  = (bf16*)(ws + 33554432);
    bf16* ab  = (bf16*)(ws + 41943040);

    cvt_all<<<8192, 256, 0, stream>>>(x, Wq, Wk, Wv, Wo, xb, wqb, wkb, wvb, wob);

    GemmArgs g1;
    g1.A = xb;
    g1.W[0] = wqb; g1.W[1] = wkb; g1.W[2] = wvb;
    g1.Yb[0] = qb; g1.Yb[1] = kb; g1.Yb[2] = vb;
    g1.scale0 = 0.125f;   // 1/sqrt(Dh)
    gemm_qkv<<<dim3(32, 24), 256, 0, stream>>>(g1);

    attn_knn<<<dim3(8, 512), 256, 0, stream>>>(qb, kb, vb, idx, ab);

    gemm_out<<<dim3(32, 16), 256, 0, stream>>>(ab, wob, out);
}

// Round 9
// 85.803 us; speedup vs baseline: 1.0745x; 1.0357x over previous
//
#include <hip/hip_runtime.h>
#include <hip/hip_bf16.h>

// Problem constants
#define B_  2
#define L_  2048
#define C_  1024
#define H_  16
#define K_  32
#define DH_ 64
#define M_  (B_ * L_)   // 4096 rows in all GEMMs

typedef __hip_bfloat16 bf16;
typedef __attribute__((ext_vector_type(4))) float f32x4;
typedef __attribute__((ext_vector_type(8))) short short8;
typedef __attribute__((ext_vector_type(8))) unsigned short u16x8;

__device__ inline unsigned short f2bf(float f) {
    __hip_bfloat16 h = __float2bfloat16(f);  // RTN
    return *reinterpret_cast<unsigned short*>(&h);
}
__device__ inline float bf2f(unsigned short u) {
    return __uint_as_float(((unsigned)u) << 16);
}
__device__ inline void gld_lds16(const bf16* g, bf16* l) {
    __builtin_amdgcn_global_load_lds(
        (const __attribute__((address_space(1))) void*)g,
        (__attribute__((address_space(3))) void*)l,
        16, 0, 0);
}

// ---------------------------------------------------------------------------
// Kernel 1: convert x, Wq, Wk, Wv, Wo from f32 to bf16 (one fused launch).
// Memory-bound at ~48 MB traffic -> ~8 us (near BW roofline).
// ---------------------------------------------------------------------------
__global__ void __launch_bounds__(256) cvt_all(
    const float* __restrict__ x,  const float* __restrict__ wq,
    const float* __restrict__ wk, const float* __restrict__ wv,
    const float* __restrict__ wo,
    bf16* __restrict__ xb,  bf16* __restrict__ wqb, bf16* __restrict__ wkb,
    bf16* __restrict__ wvb, bf16* __restrict__ wob)
{
    int g = blockIdx.x * 256 + threadIdx.x;
    const float* src; bf16* dst; int o;
    if (g < 1048576)      { src = x;  dst = xb;  o = g; }
    else if (g < 1310720) { src = wq; dst = wqb; o = g - 1048576; }
    else if (g < 1572864) { src = wk; dst = wkb; o = g - 1310720; }
    else if (g < 1835008) { src = wv; dst = wvb; o = g - 1572864; }
    else                  { src = wo; dst = wob; o = g - 1835008; }
    float4 f = reinterpret_cast<const float4*>(src)[o];
    ushort4 u;
    u.x = f2bf(f.x); u.y = f2bf(f.y); u.z = f2bf(f.z); u.w = f2bf(f.w);
    reinterpret_cast<ushort4*>(dst)[o] = u;
}

// ---------------------------------------------------------------------------
// Kernel 2: QKV NT GEMM  Y = x @ [Wq|Wk|Wv]^T  (m97 128^2 structure).
// grid (32, 24) = 768 blocks = 3/CU (implicit wave-level overlap regime).
// global_load_lds(16B) with both-sides XOR swizzle.
// ---------------------------------------------------------------------------
struct GemmArgs {
    const bf16* A;
    const bf16* W[3];
    bf16* Yb[3];
    float scale0;
};

__global__ void __launch_bounds__(256) gemm_qkv(GemmArgs ga)
{
    __shared__ bf16 As[128 * 64];   // 16 KiB
    __shared__ bf16 Bs[128 * 64];   // 16 KiB

    const int m0  = blockIdx.x * 128;
    const int nt  = blockIdx.y;
    const int seg = nt >> 3;            // 0..2 -> Wq/Wk/Wv
    const int n0  = (nt & 7) * 128;
    const bf16* __restrict__ A = ga.A;
    const bf16* __restrict__ W = ga.W[seg];
    const float scale = (seg == 0) ? ga.scale0 : 1.0f;

    const int t    = threadIdx.x;
    const int lane = t & 63;
    const int w    = t >> 6;    // wave 0..3
    const int wm   = w >> 1;    // 0..1
    const int wn   = w & 1;     // 0..1

    const int subrow = lane >> 3;   // 0..7 within an 8-row staging inst
    const int kc     = lane & 7;    // 16B chunk 0..7 within a 64-elem k row

    f32x4 acc[4][4] = {};

    for (int kt = 0; kt < 16; ++kt) {
        const int k0 = kt * 64;
        if (kt) __syncthreads();
        #pragma unroll
        for (int i = 0; i < 4; ++i) {
            const int r0  = w * 32 + i * 8;
            const int row = r0 + subrow;
            const int kcs = kc ^ (subrow & 7);   // inverse swizzle on source
            gld_lds16(A + (size_t)(m0 + row) * 1024 + k0 + kcs * 8, As + r0 * 64);
        }
        #pragma unroll
        for (int i = 0; i < 4; ++i) {
            const int r0  = w * 32 + i * 8;
            const int row = r0 + subrow;
            const int kcs = kc ^ (subrow & 7);
            gld_lds16(W + (size_t)(n0 + row) * 1024 + k0 + kcs * 8, Bs + r0 * 64);
        }
        __syncthreads();
        #pragma unroll
        for (int ks = 0; ks < 2; ++ks) {
            short8 af[4], bfv[4];
            #pragma unroll
            for (int mf = 0; mf < 4; ++mf) {
                const int row    = wm * 64 + mf * 16 + (lane & 15);
                const int kchunk = ks * 4 + (lane >> 4);
                const int pc     = kchunk ^ (row & 7);   // swizzled read
                af[mf] = *reinterpret_cast<const short8*>(As + row * 64 + pc * 8);
            }
            #pragma unroll
            for (int nf = 0; nf < 4; ++nf) {
                const int row    = wn * 64 + nf * 16 + (lane & 15);
                const int kchunk = ks * 4 + (lane >> 4);
                const int pc     = kchunk ^ (row & 7);
                bfv[nf] = *reinterpret_cast<const short8*>(Bs + row * 64 + pc * 8);
            }
            #pragma unroll
            for (int mf = 0; mf < 4; ++mf)
                #pragma unroll
                for (int nf = 0; nf < 4; ++nf)
                    acc[mf][nf] = __builtin_amdgcn_mfma_f32_16x16x32_bf16(
                        af[mf], bfv[nf], acc[mf][nf], 0, 0, 0);
        }
    }

    #pragma unroll
    for (int mf = 0; mf < 4; ++mf) {
        #pragma unroll
        for (int nf = 0; nf < 4; ++nf) {
            const int row = m0 + wm * 64 + mf * 16 + ((lane >> 4) << 2);
            const int col = n0 + wn * 64 + nf * 16 + (lane & 15);
            #pragma unroll
            for (int r = 0; r < 4; ++r)
                ga.Yb[seg][(size_t)(row + r) * 1024 + col] =
                    __float2bfloat16(acc[mf][nf][r] * scale);
        }
    }
}

// ---------------------------------------------------------------------------
// Kernel 4: output projection NT GEMM, 128x64 tile -> grid (32,16) = 512
// blocks = 2/CU (cross-block overlap of the per-K-tile barrier drain).
// f32 output to d_out.
// ---------------------------------------------------------------------------
__global__ void __launch_bounds__(256) gemm_out(
    const bf16* __restrict__ A, const bf16* __restrict__ W,
    float* __restrict__ Yf)
{
    __shared__ bf16 As[128 * 64];   // 16 KiB
    __shared__ bf16 Bs[64 * 64];    // 8 KiB

    const int m0 = blockIdx.x * 128;
    const int n0 = blockIdx.y * 64;

    const int t    = threadIdx.x;
    const int lane = t & 63;
    const int w    = t >> 6;
    const int wm   = w >> 1;    // 0..1
    const int wn   = w & 1;     // 0..1

    const int subrow = lane >> 3;
    const int kc     = lane & 7;

    f32x4 acc[4][2] = {};

    for (int kt = 0; kt < 16; ++kt) {
        const int k0 = kt * 64;
        if (kt) __syncthreads();
        #pragma unroll
        for (int i = 0; i < 4; ++i) {
            const int r0  = w * 32 + i * 8;
            const int row = r0 + subrow;
            const int kcs = kc ^ (subrow & 7);
            gld_lds16(A + (size_t)(m0 + row) * 1024 + k0 + kcs * 8, As + r0 * 64);
        }
        #pragma unroll
        for (int i = 0; i < 2; ++i) {
            const int r0  = w * 16 + i * 8;
            const int row = r0 + subrow;
            const int kcs = kc ^ (subrow & 7);
            gld_lds16(W + (size_t)(n0 + row) * 1024 + k0 + kcs * 8, Bs + r0 * 64);
        }
        __syncthreads();
        #pragma unroll
        for (int ks = 0; ks < 2; ++ks) {
            short8 af[4], bfv[2];
            #pragma unroll
            for (int mf = 0; mf < 4; ++mf) {
                const int row    = wm * 64 + mf * 16 + (lane & 15);
                const int kchunk = ks * 4 + (lane >> 4);
                const int pc     = kchunk ^ (row & 7);
                af[mf] = *reinterpret_cast<const short8*>(As + row * 64 + pc * 8);
            }
            #pragma unroll
            for (int nf = 0; nf < 2; ++nf) {
                const int row    = wn * 32 + nf * 16 + (lane & 15);
                const int kchunk = ks * 4 + (lane >> 4);
                const int pc     = kchunk ^ (row & 7);
                bfv[nf] = *reinterpret_cast<const short8*>(Bs + row * 64 + pc * 8);
            }
            #pragma unroll
            for (int mf = 0; mf < 4; ++mf)
                #pragma unroll
                for (int nf = 0; nf < 2; ++nf)
                    acc[mf][nf] = __builtin_amdgcn_mfma_f32_16x16x32_bf16(
                        af[mf], bfv[nf], acc[mf][nf], 0, 0, 0);
        }
    }

    #pragma unroll
    for (int mf = 0; mf < 4; ++mf) {
        #pragma unroll
        for (int nf = 0; nf < 2; ++nf) {
            const int row = m0 + wm * 64 + mf * 16 + ((lane >> 4) << 2);
            const int col = n0 + wn * 32 + nf * 16 + (lane & 15);
            #pragma unroll
            for (int r = 0; r < 4; ++r)
                Yf[(size_t)(row + r) * 1024 + col] = acc[mf][nf][r];
        }
    }
}

// ---------------------------------------------------------------------------
// Kernel 3: K=32 neighbor attention — wave-synchronous, no LDS, no barriers.
// 4-wave blocks (wave ww -> l = l0+ww), slot = b*4+wg pinned to XCD via
// blockIdx.x (bid%8); occupancy at the 32-waves/CU cap.  (R6 champion form;
// R3 prefetch-all, R5 pass-split, R8 32-bit addressing all null/regressed —
// this kernel sits at its L2 random-gather service floor.)
//   lane = (hw<<4)|(half<<3)|c8 ; h = wg*4+hw ; d-chunk = c8*8 (16B)
// ---------------------------------------------------------------------------
__global__ void __launch_bounds__(256) attn_knn(
    const bf16* __restrict__ qg, const bf16* __restrict__ kg,
    const bf16* __restrict__ vg, const int* __restrict__ idx,
    bf16* __restrict__ ao)
{
    const int slot = blockIdx.x;      // 0..7 -> XCD (bid%8 heuristic)
    const int b    = slot >> 2;
    const int wg   = slot & 3;
    const int l    = blockIdx.y * 4 + (threadIdx.x >> 6);

    const int lane = threadIdx.x & 63;
    const int hw   = lane >> 4;       // head within group
    const int h    = wg * 4 + hw;
    const int sl   = lane & 15;
    const int half = sl >> 3;
    const int c8   = sl & 7;

    const size_t rowq = (size_t)b * L_ + l;
    const unsigned short* kg16 = reinterpret_cast<const unsigned short*>(kg);
    const unsigned short* vg16 = reinterpret_cast<const unsigned short*>(vg);
    const size_t hoff = (size_t)h * DH_ + c8 * 8;

    int4 iv[4];
    #pragma unroll
    for (int i = 0; i < 4; ++i)
        iv[i] = reinterpret_cast<const int4*>(idx + l * K_ + half * 16)[i];

    u16x8 qv = *reinterpret_cast<const u16x8*>(
        reinterpret_cast<const unsigned short*>(qg) + rowq * C_ + hoff);
    float qf[8];
    #pragma unroll
    for (int e = 0; e < 8; ++e) qf[e] = bf2f(qv[e]);

    // ---- QK^T partial dots (16 independent 16B gathers) ----
    float s[16];
    #pragma unroll
    for (int jj = 0; jj < 16; ++jj) {
        const int4 q4 = iv[jj >> 2];
        const int row = (jj & 3) == 0 ? q4.x : (jj & 3) == 1 ? q4.y
                       : (jj & 3) == 2 ? q4.z : q4.w;
        const u16x8 kv = *reinterpret_cast<const u16x8*>(
            kg16 + ((size_t)b * L_ + row) * C_ + hoff);
        float acc = 0.f;
        #pragma unroll
        for (int e = 0; e < 8; ++e) acc += qf[e] * bf2f(kv[e]);
        s[jj] = acc;
    }

    // reduce partial dots across the 8-lane c8 group
    #pragma unroll
    for (int jj = 0; jj < 16; ++jj) {
        float x = s[jj];
        x += __shfl_xor(x, 1, 16);
        x += __shfl_xor(x, 2, 16);
        x += __shfl_xor(x, 4, 16);
        s[jj] = x;   // full score for j = half*16 + jj, in all 8 lanes
    }

    // ---- softmax in registers; 1/sum deferred to the store ----
    float m = s[0];
    #pragma unroll
    for (int jj = 1; jj < 16; ++jj) m = fmaxf(m, s[jj]);
    m = fmaxf(m, __shfl_xor(m, 8, 16));
    float ssum = 0.f;
    #pragma unroll
    for (int jj = 0; jj < 16; ++jj) { s[jj] = __expf(s[jj] - m); ssum += s[jj]; }
    ssum += __shfl_xor(ssum, 8, 16);
    const float inv = 1.0f / ssum;

    // ---- PV (16 independent 16B gathers) ----
    float acc[8] = {0.f, 0.f, 0.f, 0.f, 0.f, 0.f, 0.f, 0.f};
    #pragma unroll
    for (int jj = 0; jj < 16; ++jj) {
        const int4 q4 = iv[jj >> 2];
        const int row = (jj & 3) == 0 ? q4.x : (jj & 3) == 1 ? q4.y
                       : (jj & 3) == 2 ? q4.z : q4.w;
        const u16x8 vv = *reinterpret_cast<const u16x8*>(
            vg16 + ((size_t)b * L_ + row) * C_ + hoff);
        const float p = s[jj];
        #pragma unroll
        for (int e = 0; e < 8; ++e) acc[e] += p * bf2f(vv[e]);
    }
    #pragma unroll
    for (int e = 0; e < 8; ++e) acc[e] += __shfl_xor(acc[e], 8, 16);

    if (half == 0) {
        u16x8 o;
        #pragma unroll
        for (int e = 0; e < 8; ++e) o[e] = f2bf(acc[e] * inv);
        *reinterpret_cast<u16x8*>(ao + rowq * C_ + hoff) = o;
    }
}

// ---------------------------------------------------------------------------
// Launcher. Workspace layout (bytes):
//   xb 0 (8 MiB) | wqb 8M | wkb 10M | wvb 12M | wob 14M (2 MiB each)
//   q 16M | k 24M | v 32M | ao 40M  (8 MiB each)  -> total 48 MiB
// ---------------------------------------------------------------------------
extern "C" void kernel_launch(void* const* d_in, const int* in_sizes, int n_in,
                              void* d_out, int out_size, void* d_ws, size_t ws_size,
                              hipStream_t stream)
{
    const float* x  = (const float*)d_in[0];
    const int*   idx = (const int*)d_in[1];
    const float* Wq = (const float*)d_in[2];
    const float* Wk = (const float*)d_in[3];
    const float* Wv = (const float*)d_in[4];
    const float* Wo = (const float*)d_in[5];
    float* out = (float*)d_out;

    char* ws = (char*)d_ws;
    bf16* xb  = (bf16*)(ws + 0);
    bf16* wqb = (bf16*)(ws + 8388608);
    bf16* wkb = (bf16*)(ws + 10485760);
    bf16* wvb = (bf16*)(ws + 12582912);
    bf16* wob = (bf16*)(ws + 14680064);
    bf16* qb  = (bf16*)(ws + 16777216);
    bf16* kb  = (bf16*)(ws + 25165824);
    bf16* vb  = (bf16*)(ws + 33554432);
    bf16* ab  = (bf16*)(ws + 41943040);

    cvt_all<<<8192, 256, 0, stream>>>(x, Wq, Wk, Wv, Wo, xb, wqb, wkb, wvb, wob);

    GemmArgs g1;
    g1.A = xb;
    g1.W[0] = wqb; g1.W[1] = wkb; g1.W[2] = wvb;
    g1.Yb[0] = qb; g1.Yb[1] = kb; g1.Yb[2] = vb;
    g1.scale0 = 0.125f;   // 1/sqrt(Dh)
    gemm_qkv<<<dim3(32, 24), 256, 0, stream>>>(g1);

    attn_knn<<<dim3(8, 512), 256, 0, stream>>>(qb, kb, vb, idx, ab);

    gemm_out<<<dim3(32, 16), 256, 0, stream>>>(ab, wob, out);
}